// Round 15
// baseline (119.220 us; speedup 1.0000x reference)
//
#include <hip/hip_runtime.h>
#include <hip/hip_bf16.h>

#define NROWS 16384
#define DDIM  256
#define LOG2E 1.4426950408889634f
#define SCALE 7.213475204444817f   // (1/tau) * log2(e), tau = 0.2

typedef __attribute__((ext_vector_type(4))) float f32x4;
typedef __attribute__((ext_vector_type(2))) float f32x2;
typedef __attribute__((ext_vector_type(4))) int   i32x4;
typedef __attribute__((ext_vector_type(8))) int   i32x8;

#define UNIT_SCALE 0x7F7F7F7F   // e8m0 = 127 -> 2^0 = 1.0 in all 4 bytes

// ---------------------------------------------------------------------------
// Kernel 1: L2-normalize rows of z1,z2; quantize to OCP fp8 e4m3.
//   h1q = fp8(SCALE * h1_norm)  row-major (A side, pre-scaled for exp2)
//   h2t = fp8(h2_norm) in CHUNK-TRANSPOSED layout so simexp B-fragment loads
//         are fully coalesced 1KB global_load_dwordx4:
//         T[r>>4][ks(2)][hi(2)][q(4)][r&15][16B]  (4KB per 16-row block)
// exact fp32 diag logits diag5[i] = 5 * cos(z1_i, z2_i); zero rowsum.
// ---------------------------------------------------------------------------
__global__ __launch_bounds__(256) void prep_kernel(
    const float* __restrict__ z1, const float* __restrict__ z2,
    unsigned char* __restrict__ h1q, unsigned char* __restrict__ h2t,
    float* __restrict__ diag5, float* __restrict__ rowsum) {
  int tid = threadIdx.x;
  int w = tid >> 6, lane = tid & 63;
  int r = blockIdx.x * 4 + w;

  const float4 a = ((const float4*)z1)[r * 64 + lane];
  const float4 b = ((const float4*)z2)[r * 64 + lane];

  float ss1 = a.x * a.x + a.y * a.y + a.z * a.z + a.w * a.w;
  float ss2 = b.x * b.x + b.y * b.y + b.z * b.z + b.w * b.w;
  float dp  = a.x * b.x + a.y * b.y + a.z * b.z + a.w * b.w;
  #pragma unroll
  for (int m = 1; m <= 32; m <<= 1) {
    ss1 += __shfl_xor(ss1, m);
    ss2 += __shfl_xor(ss2, m);
    dp  += __shfl_xor(dp, m);
  }
  float inv1 = 1.0f / fmaxf(sqrtf(ss1), 1e-12f);
  float inv2 = 1.0f / fmaxf(sqrtf(ss2), 1e-12f);
  float s1 = inv1 * SCALE;         // fold 1/tau*log2e into A

  int p1 = __builtin_amdgcn_cvt_pk_fp8_f32(a.x * s1, a.y * s1, 0, false);
  p1     = __builtin_amdgcn_cvt_pk_fp8_f32(a.z * s1, a.w * s1, p1, true);
  int p2 = __builtin_amdgcn_cvt_pk_fp8_f32(b.x * inv2, b.y * inv2, 0, false);
  p2     = __builtin_amdgcn_cvt_pk_fp8_f32(b.z * inv2, b.w * inv2, p2, true);
  ((int*)h1q)[r * 64 + lane] = p1;

  // chunk-transposed h2t write: lane holds 4B at chunk c=lane>>2, sub=lane&3
  {
    int c = lane >> 2, sub = lane & 3;
    int off = (r >> 4) * 4096 + (c >> 3) * 2048 + (c & 1) * 1024 +
              ((c >> 1) & 3) * 256 + (r & 15) * 16 + sub * 4;
    *(int*)(h2t + off) = p2;
  }

  if (lane == 0) diag5[r] = dp * inv1 * inv2 * 5.0f;
  if (tid < 4) rowsum[blockIdx.x * 4 + tid] = 0.0f;  // 4096 blocks * 4 = 16384
}

// ---------------------------------------------------------------------------
// Kernel 2: rowsum_i = sum_j exp2(h1q_i . h2_j) via MX-scaled fp8 MFMA.
// ROUND 15: ONE WAVE PER SIMD, intra-wave MFMA||trans interleave.
// Cycle model from r7-r14 (all ~78-93us): per SIMD, matrix work 71K cyc
// (MfmaUtil 36% every round) + trans work 66K cyc (exp2 = quarter-rate,
// 16 cyc/wave64; VALUBusy ~42%) run ADDITIVELY. Separate pipes (m114), but
// (a) >=2 symmetric waves/SIMD convoy via resource contention, and (b) the
// compiler won't interleave exp2(t-1) with MFMA(t) intra-wave because that
// raises liveness past its 128-reg bucket.
// Fix: grid 256 = 1 block/CU, 1 wave/SIMD; amdgpu_waves_per_eu(1,2) ->
// 512-reg budget (demand ~200 -> NO squeeze/remat trigger, finally);
// 2-deep acc ping-pong (accA/accB) makes exp2(prev) independent of
// MFMA(cur); sched_group_barrier pins 1 MFMA : 3 VALU interleave (35 cyc
// matrix occupancy ~ 2x16 cyc trans + adds -> ~95% dual-pipe use from ONE
// wave, the AITER 1:1 interleave idiom applied to trans).
// Each wave: 64 rows x 4096 cols (CSPL=4) = 128 tiles; all 4 waves of a
// block stream the SAME B tiles -> L1 temporal hits keep L2 traffic low.
// No LDS, no barriers. Ideal 128 x ~590 cyc = 31us.
// ---------------------------------------------------------------------------
#define CSPL 4

#define LOADSET(B, P0, P1) do { \
  B[0] = *reinterpret_cast<const i32x4*>(P0); \
  B[1] = *reinterpret_cast<const i32x4*>(P0 + 1024); \
  B[2] = *reinterpret_cast<const i32x4*>(P0 + 2048); \
  B[3] = *reinterpret_cast<const i32x4*>(P0 + 3072); \
  B[4] = *reinterpret_cast<const i32x4*>(P1); \
  B[5] = *reinterpret_cast<const i32x4*>(P1 + 1024); \
  B[6] = *reinterpret_cast<const i32x4*>(P1 + 2048); \
  B[7] = *reinterpret_cast<const i32x4*>(P1 + 3072); \
  P0 += 8192; P1 += 8192; } while (0)

#define MFMA_S(Aop, Bop, Cop) \
  __builtin_amdgcn_mfma_scale_f32_16x16x128_f8f6f4( \
      Aop, Bop, Cop, 0, 0, 0, UNIT_SCALE, 0, UNIT_SCALE)

// 16 MFMA for one 32-col tile into ACC[0..7] (zero-C trick, no acc-init)
#define MFMA_TILE(B, ACC) do { \
  union { i32x8 v; i32x4 h[2]; } u00, u01, u10, u11; \
  u00.h[0] = B[0]; u00.h[1] = B[1]; u01.h[0] = B[2]; u01.h[1] = B[3]; \
  u10.h[0] = B[4]; u10.h[1] = B[5]; u11.h[0] = B[6]; u11.h[1] = B[7]; \
  _Pragma("unroll") for (int m = 0; m < 4; ++m) ACC[m]     = MFMA_S(afr[m][0], u00.v, ZV); \
  _Pragma("unroll") for (int m = 0; m < 4; ++m) ACC[4 + m] = MFMA_S(afr[m][0], u10.v, ZV); \
  _Pragma("unroll") for (int m = 0; m < 4; ++m) ACC[m]     = MFMA_S(afr[m][1], u01.v, ACC[m]); \
  _Pragma("unroll") for (int m = 0; m < 4; ++m) ACC[4 + m] = MFMA_S(afr[m][1], u11.v, ACC[4 + m]); \
} while (0)

// 32 exp2 + 16 pk-adds for one tile's accs (static indices under unroll)
#define EXPACC(ACC) do { \
  _Pragma("unroll") for (int q = 0; q < 8; ++q) { \
    rs2[q & 3][0] += (f32x2){__builtin_amdgcn_exp2f(ACC[q][0]), \
                             __builtin_amdgcn_exp2f(ACC[q][1])}; \
    rs2[q & 3][1] += (f32x2){__builtin_amdgcn_exp2f(ACC[q][2]), \
                             __builtin_amdgcn_exp2f(ACC[q][3])}; \
  } \
} while (0)

// pin the per-tile interleave: 8 VMEM loads, then 16 x {1 MFMA, 3 VALU}
#define SGB_TILE() do { \
  __builtin_amdgcn_sched_group_barrier(0x020, 8, 0); \
  _Pragma("unroll") for (int i_ = 0; i_ < 16; ++i_) { \
    __builtin_amdgcn_sched_group_barrier(0x008, 1, 0); \
    __builtin_amdgcn_sched_group_barrier(0x002, 3, 0); \
  } \
} while (0)

__global__ __launch_bounds__(256)
__attribute__((amdgpu_waves_per_eu(1, 2)))
void simexp_kernel(
    const unsigned char* __restrict__ h1q, const unsigned char* __restrict__ h2t,
    float* __restrict__ rowsum) {
  int tid = threadIdx.x, w = tid >> 6, lane = tid & 63;
  int bx = blockIdx.x;
  int rb = bx >> 2;        // row block 0..63 (256 rows each)
  int cs = bx & 3;         // column split 0..3 (strip = 4096 cols = 1MB)
  int row0 = rb * 256 + w * 64;

  const char* h1b = (const char*)h1q;

  // A fragments: 4 row-subtiles x 2 k128-steps, 32 fp8 each -> 64 VGPRs
  i32x8 afr[4][2];
  #pragma unroll
  for (int m = 0; m < 4; ++m)
    #pragma unroll
    for (int ks = 0; ks < 2; ++ks) {
      int row = row0 + m * 16 + (lane & 15);
      int off = row * 256 + ks * 128 + (lane >> 4) * 32;   // 32B aligned
      afr[m][ks] = *reinterpret_cast<const i32x8*>(h1b + off);
    }
  #pragma unroll
  for (int m = 0; m < 4; ++m)
    #pragma unroll
    for (int ks = 0; ks < 2; ++ks)
      asm volatile("" : "+v"(afr[m][ks]));   // keep resident

  // B-fragment base pointers into the chunk-transposed strip
  const char* Bp0 = (const char*)h2t + (size_t)cs * 1048576 + lane * 16;
  const char* Bp1 = Bp0 + 4096;

  const f32x4 ZV = {0.f, 0.f, 0.f, 0.f};
  f32x2 rs2[4][2];
  #pragma unroll
  for (int m = 0; m < 4; ++m) {
    rs2[m][0] = (f32x2){0.f, 0.f};
    rs2[m][1] = (f32x2){0.f, 0.f};
  }

  i32x4 bufA[8], bufB[8];
  f32x4 accA[8], accB[8];

  LOADSET(bufA, Bp0, Bp1);          // prime tile 0

  for (int k = 0; k < 64; ++k) {
    LOADSET(bufB, Bp0, Bp1);        // prefetch tile 2k+1
    MFMA_TILE(bufA, accA);          // matrix: tile 2k
    if (k) EXPACC(accB);            // trans:  tile 2k-1 (overlaps MFMA above)
    SGB_TILE();
    LOADSET(bufA, Bp0, Bp1);        // prefetch tile 2k+2 (k=63: OOB -> slack)
    MFMA_TILE(bufB, accB);          // matrix: tile 2k+1
    EXPACC(accA);                   // trans:  tile 2k
    SGB_TILE();
  }
  EXPACC(accB);                     // pipeline tail: tile 127

  // reduce the 16 column-lanes (lane&15) and add to global rowsum
  #pragma unroll
  for (int m = 0; m < 4; ++m)
    #pragma unroll
    for (int p = 0; p < 2; ++p)
      #pragma unroll
      for (int c = 0; c < 2; ++c) {
        float v = rs2[m][p][c];
        v += __shfl_xor(v, 1);
        v += __shfl_xor(v, 2);
        v += __shfl_xor(v, 4);
        v += __shfl_xor(v, 8);
        if ((lane & 15) == 0)
          atomicAdd(&rowsum[row0 + m * 16 + (lane >> 4) * 4 + p * 2 + c], v);
      }
}

// ---------------------------------------------------------------------------
// Kernel 3: loss = sum_i [ log(rowsum_i - exp(diag5_i)) - diag5_i ]
// ---------------------------------------------------------------------------
__global__ __launch_bounds__(1024) void loss_kernel(
    const float* __restrict__ rowsum, const float* __restrict__ diag5,
    float* __restrict__ out) {
  int tid = threadIdx.x;
  float s = 0.0f;
  for (int i = tid; i < NROWS; i += 1024) {
    float d5 = diag5[i];
    float de = __builtin_amdgcn_exp2f(d5 * LOG2E);
    s += logf(rowsum[i] - de) - d5;
  }
  #pragma unroll
  for (int m = 1; m <= 32; m <<= 1) s += __shfl_xor(s, m);
  __shared__ float wsum[16];
  if ((tid & 63) == 0) wsum[tid >> 6] = s;
  __syncthreads();
  if (tid == 0) {
    float t = 0.0f;
    #pragma unroll
    for (int i = 0; i < 16; ++i) t += wsum[i];
    out[0] = t;
  }
}

// ---------------------------------------------------------------------------
extern "C" void kernel_launch(void* const* d_in, const int* in_sizes, int n_in,
                              void* d_out, int out_size, void* d_ws, size_t ws_size,
                              hipStream_t stream) {
  const float* z1 = (const float*)d_in[0];
  const float* z2 = (const float*)d_in[1];

  char* ws = (char*)d_ws;
  unsigned char* h1q = (unsigned char*)(ws);             // 4 MB
  unsigned char* h2t = (unsigned char*)(ws + 4194304);   // 4 MB + 32KB slack
  float* diag5 = (float*)(ws + 8421376);                 // 64 KB
  float* rowsm = (float*)(ws + 8486912);                 // 64 KB
  if (ws_size < 8552448) return;                         // fail loudly

  prep_kernel<<<4096, 256, 0, stream>>>(z1, z2, h1q, h2t, diag5, rowsm);
  simexp_kernel<<<256, 256, 0, stream>>>(h1q, h2t, rowsm);
  loss_kernel<<<1, 1024, 0, stream>>>(rowsm, diag5, (float*)d_out);
}